// Round 7
// baseline (1914.464 us; speedup 1.0000x reference)
//
#include <hip/hip_runtime.h>

using int32x4 = __attribute__((ext_vector_type(4))) int;

#define BM 256
#define BN 256
#define TBUF 32768   // one K-tile buffer: A(16K) + B(16K); K-tile = 64 bytes of K

// ---------------------------------------------------------------------------
// Kernel 1: pack int32 activations -> int8 (values in [-128,127])
// ---------------------------------------------------------------------------
__global__ __launch_bounds__(256) void pack_x_kernel(const int32x4* __restrict__ x,
                                                     int32x4* __restrict__ xp,
                                                     int nvec) {
    int t = blockIdx.x * 256 + threadIdx.x;
    if (t >= nvec) return;
    int32x4 a = x[t * 4 + 0];
    int32x4 b = x[t * 4 + 1];
    int32x4 c = x[t * 4 + 2];
    int32x4 d = x[t * 4 + 3];
    int32x4 o;
    o.x = (a.x & 255) | ((a.y & 255) << 8) | ((a.z & 255) << 16) | (a.w << 24);
    o.y = (b.x & 255) | ((b.y & 255) << 8) | ((b.z & 255) << 16) | (b.w << 24);
    o.z = (c.x & 255) | ((c.y & 255) << 8) | ((c.z & 255) << 16) | (c.w << 24);
    o.w = (d.x & 255) | ((d.y & 255) << 8) | ((d.z & 255) << 16) | (d.w << 24);
    xp[t] = o;
}

// ---------------------------------------------------------------------------
// Kernel 2: weight transform — int32 [K][N] -> int8 [N][K]
// ---------------------------------------------------------------------------
__global__ __launch_bounds__(256) void transform_w_kernel(const int* __restrict__ w,
                                                          unsigned char* __restrict__ wt,
                                                          int K, int N) {
    __shared__ unsigned char tileT[64][72];
    int tx = threadIdx.x & 15;
    int ty = threadIdx.x >> 4;
    int n0 = blockIdx.x * 64;
    int k0 = blockIdx.y * 64;
#pragma unroll
    for (int r = 0; r < 4; ++r) {
        int row = ty * 4 + r;  // k_local
        int32x4 v = *(const int32x4*)&w[(size_t)(k0 + row) * N + n0 + tx * 4];
        tileT[tx * 4 + 0][row] = (unsigned char)(v.x & 255);
        tileT[tx * 4 + 1][row] = (unsigned char)(v.y & 255);
        tileT[tx * 4 + 2][row] = (unsigned char)(v.z & 255);
        tileT[tx * 4 + 3][row] = (unsigned char)(v.w & 255);
    }
    __syncthreads();
#pragma unroll
    for (int r = 0; r < 4; ++r) {
        int row = ty * 4 + r;  // n_local
        uchar4 v = *(const uchar4*)&tileT[row][tx * 4];
        *(uchar4*)&wt[(size_t)(n0 + row) * K + k0 + tx * 4] = v;
    }
}

// ---------------------------------------------------------------------------
// Kernel 3: int8 GEMM, 256x256 tile, 16x16x64 MFMA (verified 0-conflict
// family), 2-deep LDS (64 KiB -> 2 blocks/CU), register double-buffered
// fragments, ONE mid-tile barrier per K-tile, wave-exact vmcnt ledger.
// ---------------------------------------------------------------------------
__global__ __launch_bounds__(512, 4) void gemm_i8_2d(
    const char* __restrict__ A,   // [M][K] int8
    const char* __restrict__ Bt,  // [N][K] int8
    const int* __restrict__ bias,
    const int* __restrict__ shiftp,
    int* __restrict__ C,          // [M][N]
    int M, int N, int K) {
    __shared__ char smem[2 * TBUF];  // 64 KiB -> 2 blocks/CU

    const int nbn = N / BN;
    const int nwg = gridDim.x;
    const int bid = blockIdx.x;
    const int cpx = nwg >> 3;  // nwg % 8 == 0 -> bijective XCD swizzle
    const int swz = (bid & 7) * cpx + (bid >> 3);
    const int m0 = (swz / nbn) * BM;
    const int n0 = (swz % nbn) * BN;

    const int t = threadIdx.x;
    const int lane = t & 63;
    const int wave = t >> 6;
    const int wr = wave >> 2;  // 0..1  (M half, 128 rows)
    const int wc = wave & 3;   // 0..3  (N quarter, 64 cols)

    // ---- staging geometry (pre-swizzled global source, linear LDS dest) ----
    const int s_row = t >> 2;
    const int s_col = ((t & 3) << 4) ^ (((t >> 3) & 3) << 4);
    const char* a_src = A + (size_t)(m0 + s_row) * K + s_col;
    const char* b_src = Bt + (size_t)(n0 + s_row) * K + s_col;
    const size_t jstr = (size_t)128 * K;
    char* lds_st = smem + t * 16;

    // ---- fragment-read geometry (verified 16 rows x 4 col-groups family) ----
    const int lr = lane & 15;
    const int lc = (lane >> 4) << 4;
    const int xr = ((lr >> 1) & 3) << 4;
    const int a_off = ((wr << 7) + lr) * 64 + (lc ^ xr);          // + mf*1024
    const int b_off = 16384 + ((wc << 6) + lr) * 64 + (lc ^ xr);  // + nf*1024

    int32x4 acc[8][4] = {};
    int32x4 afX[4], afY[4], bfX[4], bfY[4];

    const int nt = K / 64;  // 64 K-tiles (even, >= 4)

#define GLL(src, dst)                                                 \
    __builtin_amdgcn_global_load_lds(                                 \
        (const __attribute__((address_space(1))) void*)(src),        \
        (__attribute__((address_space(3))) void*)(dst), 16, 0, 0)

#define FENCE asm volatile("" ::: "memory")
#define BARR                           \
    do {                               \
        FENCE;                         \
        __builtin_amdgcn_s_barrier();  \
        FENCE;                         \
    } while (0)
#define SB0 __builtin_amdgcn_sched_barrier(0)
#define LGKM0                                                   \
    do {                                                        \
        asm volatile("s_waitcnt lgkmcnt(0)" ::: "memory");      \
        SB0;                                                    \
    } while (0)
#define VMW(n)                                                  \
    do {                                                        \
        asm volatile("s_waitcnt vmcnt(" #n ")" ::: "memory");   \
        SB0;                                                    \
    } while (0)

    // One K-tile, 2-deep ledger. Entry: afX/BFC hold tile TT; buf TT&1 = tile
    // TT data; buf (TT+1)&1 = tile TT+1 data (each wave's own stage drained,
    // barrier joined). Sequence:
    //   a) afY reads (buf cur)        b) burst1 (afX x BFC)
    //   c) lgkm0 (afY + all cur-buf reads done); vmcnt0 (stage TT+1 drained)
    //   d) BARR  -- publishes stage(TT+1), licenses overwrite of buf cur
    //   e) stage(TT+2) -> buf cur ; read next-tile X (afX', BFN) from buf nxt
    //   f) burst2 (afY x BFC)         g) lgkm0 (next X landed)
#define TILE(TT, BFC, BFN, DOSTAGE, DOREADN, DOVMW)                                    \
    do {                                                                               \
        const int base_ = ((TT) & 1) * TBUF;                                           \
        const int nbase_ = (((TT) + 1) & 1) * TBUF;                                    \
        const size_t kc_ = (size_t)((TT) + 2) * 64;                                    \
        _Pragma("unroll") for (int i = 0; i < 4; ++i)                                  \
            afY[i] = *(const int32x4*)&smem[base_ + a_off + (4 + i) * 1024];           \
        SB0;                                                                           \
        __builtin_amdgcn_s_setprio(1);                                                 \
        _Pragma("unroll") for (int mi = 0; mi < 4; ++mi)                               \
            _Pragma("unroll") for (int ni = 0; ni < 4; ++ni)                           \
                acc[mi][ni] = __builtin_amdgcn_mfma_i32_16x16x64_i8(                   \
                    afX[mi], BFC[ni], acc[mi][ni], 0, 0, 0);                           \
        __builtin_amdgcn_s_setprio(0);                                                 \
        LGKM0;                                                                         \
        if (DOVMW) VMW(0);                                                             \
        BARR;                                                                          \
        if (DOSTAGE) {                                                                 \
            GLL(a_src + kc_, lds_st + base_);                                          \
            GLL(a_src + jstr + kc_, lds_st + base_ + 8192);                            \
            GLL(b_src + kc_, lds_st + base_ + 16384);                                  \
            GLL(b_src + jstr + kc_, lds_st + base_ + 24576);                           \
        }                                                                              \
        if (DOREADN) {                                                                 \
            _Pragma("unroll") for (int i = 0; i < 4; ++i)                              \
                afX[i] = *(const int32x4*)&smem[nbase_ + a_off + i * 1024];            \
            _Pragma("unroll") for (int i = 0; i < 4; ++i)                              \
                BFN[i] = *(const int32x4*)&smem[nbase_ + b_off + i * 1024];            \
        }                                                                              \
        SB0;                                                                           \
        __builtin_amdgcn_s_setprio(1);                                                 \
        _Pragma("unroll") for (int mi = 0; mi < 4; ++mi)                               \
            _Pragma("unroll") for (int ni = 0; ni < 4; ++ni)                           \
                acc[4 + mi][ni] = __builtin_amdgcn_mfma_i32_16x16x64_i8(               \
                    afY[mi], BFC[ni], acc[4 + mi][ni], 0, 0, 0);                       \
        __builtin_amdgcn_s_setprio(0);                                                 \
        if (DOREADN) LGKM0;                                                            \
    } while (0)

    // ---- prologue: stage tiles 0 (buf0) and 1 (buf1) ----
#pragma unroll
    for (int p = 0; p < 2; ++p) {
        GLL(a_src + p * 64, lds_st + p * TBUF);
        GLL(a_src + jstr + p * 64, lds_st + p * TBUF + 8192);
        GLL(b_src + p * 64, lds_st + p * TBUF + 16384);
        GLL(b_src + jstr + p * 64, lds_st + p * TBUF + 24576);
    }
    VMW(4);  // tile 0's 4 loads done; tile 1's in flight
    BARR;
    // preload X(0) from buf0
#pragma unroll
    for (int i = 0; i < 4; ++i) afX[i] = *(const int32x4*)&smem[a_off + i * 1024];
#pragma unroll
    for (int i = 0; i < 4; ++i) bfX[i] = *(const int32x4*)&smem[b_off + i * 1024];
    LGKM0;

    // ---- main loop ----
    int tt = 0;
    for (; tt < nt - 2; tt += 2) {
        TILE(tt, bfX, bfY, 1, 1, 1);
        TILE(tt + 1, bfY, bfX, 1, 1, 1);
    }
    // tt == nt-2 (even): no more staging; still drain stage(nt-1) before its reads
    TILE(nt - 2, bfX, bfY, 0, 1, 1);
    TILE(nt - 1, bfY, bfX, 0, 0, 0);

    // ---- epilogue: bias + shift, int32 store (16x16 C/D layout) ----
    const int s = *shiftp;
    const int crow = (lane >> 4) << 2;
    const int ccol = lane & 15;
    int bv[4];
#pragma unroll
    for (int nf = 0; nf < 4; ++nf) bv[nf] = bias[n0 + wc * 64 + nf * 16 + ccol];
#pragma unroll
    for (int mf = 0; mf < 8; ++mf) {
        const int grow0 = m0 + wr * 128 + mf * 16 + crow;
#pragma unroll
        for (int nf = 0; nf < 4; ++nf) {
            const int gcol = n0 + wc * 64 + nf * 16 + ccol;
#pragma unroll
            for (int r = 0; r < 4; ++r) {
                int y = acc[mf][nf][r] + bv[nf];
                y = (s > 0) ? (y >> s) : y;
                C[(size_t)(grow0 + r) * N + gcol] = y;
            }
        }
    }
#undef GLL
#undef FENCE
#undef BARR
#undef SB0
#undef LGKM0
#undef VMW
#undef TILE
}

// ---------------------------------------------------------------------------
extern "C" void kernel_launch(void* const* d_in, const int* in_sizes, int n_in,
                              void* d_out, int out_size, void* d_ws, size_t ws_size,
                              hipStream_t stream) {
    const int* x = (const int*)d_in[0];
    const int* w = (const int*)d_in[1];   // int8 values stored as int32
    const int* bias = (const int*)d_in[2];
    const int* shiftp = (const int*)d_in[3];
    int* out = (int*)d_out;

    const int N = in_sizes[2];      // 4096
    const int K = in_sizes[1] / N;  // 4096
    const int M = in_sizes[0] / K;  // 8192

    char* xp = (char*)d_ws;
    unsigned char* wt = (unsigned char*)d_ws + (size_t)M * K;

    int nvec = (int)(((long long)M * K) / 16);
    pack_x_kernel<<<(nvec + 255) / 256, 256, 0, stream>>>((const int32x4*)x, (int32x4*)xp, nvec);

    dim3 tgrid(N / 64, K / 64);
    transform_w_kernel<<<tgrid, 256, 0, stream>>>(w, wt, K, N);

    int nwg = (M / BM) * (N / BN);  // 512, %8==0
    gemm_i8_2d<<<nwg, 512, 0, stream>>>(xp, (const char*)wt, bias, shiftp, out, M, N, K);
}

// Round 8
// 197.068 us; speedup vs baseline: 9.7148x; 9.7148x over previous
//
#include <hip/hip_runtime.h>

using int32x4 = __attribute__((ext_vector_type(4))) int;

#define BM 256
#define BN 128
#define TBUF 24576   // one K-tile buffer: A 16K (256 rows x 64B) + B 8K (128 rows)

// ---------------------------------------------------------------------------
// Kernel 1: pack int32 activations -> int8 (values in [-128,127])
// ---------------------------------------------------------------------------
__global__ __launch_bounds__(256) void pack_x_kernel(const int32x4* __restrict__ x,
                                                     int32x4* __restrict__ xp,
                                                     int nvec) {
    int t = blockIdx.x * 256 + threadIdx.x;
    if (t >= nvec) return;
    int32x4 a = x[t * 4 + 0];
    int32x4 b = x[t * 4 + 1];
    int32x4 c = x[t * 4 + 2];
    int32x4 d = x[t * 4 + 3];
    int32x4 o;
    o.x = (a.x & 255) | ((a.y & 255) << 8) | ((a.z & 255) << 16) | (a.w << 24);
    o.y = (b.x & 255) | ((b.y & 255) << 8) | ((b.z & 255) << 16) | (b.w << 24);
    o.z = (c.x & 255) | ((c.y & 255) << 8) | ((c.z & 255) << 16) | (c.w << 24);
    o.w = (d.x & 255) | ((d.y & 255) << 8) | ((d.z & 255) << 16) | (d.w << 24);
    xp[t] = o;
}

// ---------------------------------------------------------------------------
// Kernel 2: weight transform — int32 [K][N] -> int8 [N][K]
// ---------------------------------------------------------------------------
__global__ __launch_bounds__(256) void transform_w_kernel(const int* __restrict__ w,
                                                          unsigned char* __restrict__ wt,
                                                          int K, int N) {
    __shared__ unsigned char tileT[64][72];
    int tx = threadIdx.x & 15;
    int ty = threadIdx.x >> 4;
    int n0 = blockIdx.x * 64;
    int k0 = blockIdx.y * 64;
#pragma unroll
    for (int r = 0; r < 4; ++r) {
        int row = ty * 4 + r;  // k_local
        int32x4 v = *(const int32x4*)&w[(size_t)(k0 + row) * N + n0 + tx * 4];
        tileT[tx * 4 + 0][row] = (unsigned char)(v.x & 255);
        tileT[tx * 4 + 1][row] = (unsigned char)(v.y & 255);
        tileT[tx * 4 + 2][row] = (unsigned char)(v.z & 255);
        tileT[tx * 4 + 3][row] = (unsigned char)(v.w & 255);
    }
    __syncthreads();
#pragma unroll
    for (int r = 0; r < 4; ++r) {
        int row = ty * 4 + r;  // n_local
        uchar4 v = *(const uchar4*)&tileT[row][tx * 4];
        *(uchar4*)&wt[(size_t)(n0 + row) * K + k0 + tx * 4] = v;
    }
}

// ---------------------------------------------------------------------------
// Kernel 3: int8 GEMM. 256x128 tile, 256 threads (4 waves, 2Mx2N), 16x16x64
// MFMA with the verified 0-conflict fragment family, 3-deep 24KiB LDS ring
// (72 KiB total -> 2 blocks/CU for cross-block stall coverage), one barrier
// per K-tile, wave-exact counted-vmcnt ledger (no cross-wave read races).
// ---------------------------------------------------------------------------
__global__ __launch_bounds__(256, 2) void gemm_i8_3d(
    const char* __restrict__ A,   // [M][K] int8
    const char* __restrict__ Bt,  // [N][K] int8
    const int* __restrict__ bias,
    const int* __restrict__ shiftp,
    int* __restrict__ C,          // [M][N]
    int M, int N, int K) {
    __shared__ char smem[3 * TBUF];  // 72 KiB

    const int nbn = N / BN;  // 32
    const int nwg = gridDim.x;
    const int bid = blockIdx.x;
    const int cpx = nwg >> 3;  // nwg % 8 == 0 -> bijective XCD swizzle
    const int swz = (bid & 7) * cpx + (bid >> 3);
    const int m0 = (swz / nbn) * BM;
    const int n0 = (swz % nbn) * BN;

    const int t = threadIdx.x;
    const int lane = t & 63;
    const int wave = t >> 6;   // 0..3
    const int wr = wave >> 1;  // 0..1  (M half, 128 rows)
    const int wc = wave & 1;   // 0..1  (N half, 64 cols)

    // ---- staging geometry (pre-swizzled global source, linear LDS dest) ----
    // 256 threads x 16B = 4 KiB per GLL = 64 rows of 64B.
    const int s_row = t >> 2;                                   // 0..63
    const int s_col = ((t & 3) << 4) ^ (((t >> 3) & 3) << 4);   // xor(row bits 1-2)
    const char* a_src = A + (size_t)(m0 + s_row) * K + s_col;
    const char* b_src = Bt + (size_t)(n0 + s_row) * K + s_col;
    const size_t jstr = (size_t)64 * K;  // 64 rows per GLL chunk
    char* lds_st = smem + t * 16;

    // ---- fragment-read geometry (verified 16-rows x 4-col-groups family) ----
    const int lr = lane & 15;
    const int lc = (lane >> 4) << 4;
    const int xr = ((lr >> 1) & 3) << 4;
    const int a_off = ((wr << 7) + lr) * 64 + (lc ^ xr);          // + mf*1024, mf 0..7
    const int b_off = 16384 + ((wc << 6) + lr) * 64 + (lc ^ xr);  // + nf*1024, nf 0..3

    int32x4 acc[8][4] = {};
    int32x4 af[4], ay[4], bf[4];

    const int nt = K / 64;  // 64 K-tiles

#define GLL(src, dst)                                                 \
    __builtin_amdgcn_global_load_lds(                                 \
        (const __attribute__((address_space(1))) void*)(src),        \
        (__attribute__((address_space(3))) void*)(dst), 16, 0, 0)

#define FENCE asm volatile("" ::: "memory")
#define BARR                           \
    do {                               \
        FENCE;                         \
        __builtin_amdgcn_s_barrier();  \
        FENCE;                         \
    } while (0)
#define SB0 __builtin_amdgcn_sched_barrier(0)
#define LGKM(n)                                                   \
    do {                                                          \
        asm volatile("s_waitcnt lgkmcnt(" #n ")" ::: "memory");   \
        SB0;                                                      \
    } while (0)
#define VMW(n)                                                  \
    do {                                                        \
        asm volatile("s_waitcnt vmcnt(" #n ")" ::: "memory");   \
        SB0;                                                    \
    } while (0)

    // ---- prologue: stage tiles 0 (buf0) and 1 (buf1), 6 GLL each ----
#pragma unroll
    for (int p = 0; p < 2; ++p) {
#pragma unroll
        for (int j = 0; j < 4; ++j)
            GLL(a_src + (size_t)p * 64 + j * jstr, lds_st + p * TBUF + j * 4096);
#pragma unroll
        for (int j = 0; j < 2; ++j)
            GLL(b_src + (size_t)p * 64 + j * jstr, lds_st + p * TBUF + 16384 + j * 4096);
    }
    VMW(6);  // own stage(0) chunks done; stage(1) in flight

    // ---- main loop: one barrier per K-tile ----
    // Ledger (wave-exact): end-of-tile-t VMW(6) sees {stage(t+1), stage(t+2)}
    // outstanding and drains stage(t+1); tile-(t+1)'s top BARR then publishes
    // it to all waves BEFORE any wave reads buf (t+1). No mid-tile cross-wave
    // reads exist, so there is no read-before-publish window.
    for (int tt = 0; tt < nt; ++tt) {
        const int base = (tt % 3) * TBUF;
        const int sb = ((tt + 2) % 3) * TBUF;
        const size_t kc = (size_t)(tt + 2) * 64;
        const bool st = (tt + 2) < nt;

        BARR;  // publishes stage(tt); licenses overwrite of buf (tt+2)%3
        // top reads: all 12 frag reads issued up front
#pragma unroll
        for (int i = 0; i < 4; ++i) af[i] = *(const int32x4*)&smem[base + a_off + i * 1024];
#pragma unroll
        for (int i = 0; i < 4; ++i) bf[i] = *(const int32x4*)&smem[base + b_off + i * 1024];
#pragma unroll
        for (int i = 0; i < 4; ++i) ay[i] = *(const int32x4*)&smem[base + a_off + (4 + i) * 1024];
        if (st) {  // stage A of tile tt+2 (4 GLL)
#pragma unroll
            for (int j = 0; j < 4; ++j)
                GLL(a_src + kc + j * jstr, lds_st + sb + j * 4096);
        }
        LGKM(4);  // af+bf (oldest 8) done; ay may still be in flight
        __builtin_amdgcn_s_setprio(1);
#pragma unroll
        for (int mi = 0; mi < 4; ++mi)
#pragma unroll
            for (int ni = 0; ni < 4; ++ni)
                acc[mi][ni] = __builtin_amdgcn_mfma_i32_16x16x64_i8(af[mi], bf[ni], acc[mi][ni], 0, 0, 0);
        __builtin_amdgcn_s_setprio(0);
        if (st) {  // stage B of tile tt+2 (2 GLL)
#pragma unroll
            for (int j = 0; j < 2; ++j)
                GLL(b_src + kc + j * jstr, lds_st + sb + 16384 + j * 4096);
        }
        LGKM(0);  // ay landed under burst 1
        __builtin_amdgcn_s_setprio(1);
#pragma unroll
        for (int mi = 0; mi < 4; ++mi)
#pragma unroll
            for (int ni = 0; ni < 4; ++ni)
                acc[4 + mi][ni] = __builtin_amdgcn_mfma_i32_16x16x64_i8(ay[mi], bf[ni], acc[4 + mi][ni], 0, 0, 0);
        __builtin_amdgcn_s_setprio(0);
        // tail wait: drain stage(tt+1) before next tile's barrier publishes it
        if (tt < nt - 2) {
            VMW(6);
        } else if (tt == nt - 2) {
            VMW(0);
        }
    }

    // ---- epilogue: bias + shift, int32 store (16x16 C/D layout) ----
    const int s = *shiftp;
    const int crow = (lane >> 4) << 2;
    const int ccol = lane & 15;
    int bv[4];
#pragma unroll
    for (int nf = 0; nf < 4; ++nf) bv[nf] = bias[n0 + wc * 64 + nf * 16 + ccol];
#pragma unroll
    for (int mf = 0; mf < 8; ++mf) {
        const int grow0 = m0 + wr * 128 + mf * 16 + crow;
#pragma unroll
        for (int nf = 0; nf < 4; ++nf) {
            const int gcol = n0 + wc * 64 + nf * 16 + ccol;
#pragma unroll
            for (int r = 0; r < 4; ++r) {
                int y = acc[mf][nf][r] + bv[nf];
                y = (s > 0) ? (y >> s) : y;
                C[(size_t)(grow0 + r) * N + gcol] = y;
            }
        }
    }
#undef GLL
#undef FENCE
#undef BARR
#undef SB0
#undef LGKM
#undef VMW
}

// ---------------------------------------------------------------------------
extern "C" void kernel_launch(void* const* d_in, const int* in_sizes, int n_in,
                              void* d_out, int out_size, void* d_ws, size_t ws_size,
                              hipStream_t stream) {
    const int* x = (const int*)d_in[0];
    const int* w = (const int*)d_in[1];   // int8 values stored as int32
    const int* bias = (const int*)d_in[2];
    const int* shiftp = (const int*)d_in[3];
    int* out = (int*)d_out;

    const int N = in_sizes[2];      // 4096
    const int K = in_sizes[1] / N;  // 4096
    const int M = in_sizes[0] / K;  // 8192

    char* xp = (char*)d_ws;
    unsigned char* wt = (unsigned char*)d_ws + (size_t)M * K;

    int nvec = (int)(((long long)M * K) / 16);
    pack_x_kernel<<<(nvec + 255) / 256, 256, 0, stream>>>((const int32x4*)x, (int32x4*)xp, nvec);

    dim3 tgrid(N / 64, K / 64);
    transform_w_kernel<<<tgrid, 256, 0, stream>>>(w, wt, K, N);

    int nwg = (M / BM) * (N / BN);  // 32 * 32 = 1024, %8==0
    gemm_i8_3d<<<nwg, 256, 0, stream>>>(xp, (const char*)wt, bias, shiftp, out, M, N, K);
}